// Round 11
// baseline (374.563 us; speedup 1.0000x reference)
//
#include <hip/hip_runtime.h>
#include <hip/hip_bf16.h>
#include <math.h>
#include <cstddef>

#define EPS 1e-5f

typedef __attribute__((ext_vector_type(8))) short bf16x8;
typedef __attribute__((ext_vector_type(4))) short bf16x4;
typedef __attribute__((ext_vector_type(4))) float f32x4;

__device__ __forceinline__ float wave_sum(float v) {
#pragma unroll
  for (int o = 32; o > 0; o >>= 1) v += __shfl_xor(v, o, 64);
  return v;
}

// fp32 -> bf16 bits, round-to-nearest-even (finite inputs only)
__device__ __forceinline__ unsigned short f2b(float f) {
  union { float f; unsigned int u; } v; v.f = f;
  unsigned int r = (v.u + 0x7FFFu + ((v.u >> 16) & 1u)) >> 16;
  return (unsigned short)r;
}
__device__ __forceinline__ float b2f(unsigned short u) {
  union { unsigned int u; float f; } v; v.u = ((unsigned int)u) << 16;
  return v.f;
}
// packed pair convert (RNE)
__device__ __forceinline__ ushort2 pk2b(float a, float b) {
  __hip_bfloat162 h = __float22bfloat162_rn(make_float2(a, b));
  union { __hip_bfloat162 h; ushort2 u; } v;
  v.h = h;
  return v.u;
}

// ============ Weight pre-conversion: fp32 -> bf16, 8 arrays in one launch ==
struct WConvArgs {
  const float* src[8];
  unsigned short* dst[8];
  int n[8];
};
__global__ __launch_bounds__(256) void conv_w(WConvArgs a) {
  const int arr = blockIdx.y;
  const int i = (blockIdx.x * 256 + threadIdx.x) * 4;
  if (i >= a.n[arr]) return;
  const float4 f = *(const float4*)(a.src[arr] + i);
  unsigned short* d = a.dst[arr] + i;
  *(ushort2*)d = pk2b(f.x, f.y);
  *(ushort2*)(d + 2) = pk2b(f.z, f.w);
}

// ============ MFMA GEMM 32x64 (qkv only): C = A @ W^T + bias ==============
// W pre-converted bf16. 4 waves, double-buffered LDS, 1 barrier/K-step.
// SCALEQ: multiply columns [0,512) by 0.125 (q scale for attention).
template <int SCALEQ>
__global__ __launch_bounds__(256) void gemm32(
    const unsigned short* __restrict__ Aptr, const unsigned short* __restrict__ W,
    const float* __restrict__ bias, unsigned short* __restrict__ Cb,
    int M, int N, int K) {
  __shared__ __align__(16) unsigned short As[2][32][72];
  __shared__ __align__(16) unsigned short Ws[2][64][72];
  const int tid = threadIdx.x;
  const int wid = tid >> 6, lane = tid & 63;
  const int ln = lane & 15, quad = lane >> 4;
  const int m0 = blockIdx.x * 32, n0 = blockIdx.y * 64;
  const int arow = tid >> 3, aseg = tid & 7;   // A: 8 threads/row, 8 elems
  const int wrow = tid >> 2, wseg = tid & 3;   // W: 4 threads/row, 16 elems
  const int KS = K >> 6;

  bf16x8 ra;
  bf16x8 rwb0, rwb1;

  auto load_tile = [&](int ks) {
    const int k0 = ks * 64;
    ra = *(const bf16x8*)(Aptr + (size_t)(m0 + arow) * K + k0 + aseg * 8);
    const unsigned short* wp = W + (size_t)(n0 + wrow) * K + k0 + wseg * 16;
    rwb0 = *(const bf16x8*)wp;
    rwb1 = *(const bf16x8*)(wp + 8);
  };
  auto store_tile = [&](int buf) {
    *(bf16x8*)&As[buf][arow][aseg * 8] = ra;
    *(bf16x8*)&Ws[buf][wrow][wseg * 16] = rwb0;
    *(bf16x8*)&Ws[buf][wrow][wseg * 16 + 8] = rwb1;
  };

  f32x4 acc[2];
  acc[0] = (f32x4){0.f, 0.f, 0.f, 0.f};
  acc[1] = (f32x4){0.f, 0.f, 0.f, 0.f};
  const int mrow = (wid & 1) * 16, nh = wid >> 1;

  load_tile(0);
  store_tile(0);
  __syncthreads();

#pragma unroll 1
  for (int ks = 0; ks < KS; ++ks) {
    const int cur = ks & 1;
    if (ks + 1 < KS) load_tile(ks + 1);
#pragma unroll
    for (int kc = 0; kc < 2; ++kc) {
      bf16x8 af = *(const bf16x8*)&As[cur][mrow + ln][kc * 32 + quad * 8];
#pragma unroll
      for (int nt = 0; nt < 2; ++nt) {
        bf16x8 wf = *(const bf16x8*)&Ws[cur][nh * 32 + nt * 16 + ln][kc * 32 + quad * 8];
        acc[nt] = __builtin_amdgcn_mfma_f32_16x16x32_bf16(af, wf, acc[nt], 0, 0, 0);
      }
    }
    if (ks + 1 < KS) store_tile(cur ^ 1);
    __syncthreads();
  }

  const int gm = m0 + mrow + quad * 4;
  const float qs = (SCALEQ && n0 < 512) ? 0.125f : 1.f;
#pragma unroll
  for (int nt = 0; nt < 2; ++nt) {
    const int gn = n0 + nh * 32 + nt * 16 + ln;
    float bv = bias[gn];
#pragma unroll
    for (int r = 0; r < 4; ++r) {
      float v = (acc[nt][r] + bv) * qs;
      Cb[(size_t)(gm + r) * N + gn] = f2b(v);
    }
  }
}

// ============ MFMA GEMM 16x64: C = A @ W^T + bias ==========================
// Half-height tile -> 2x blocks (1024 for N=512) = 4 blocks/CU resident;
// barrier drains overlap across blocks. LDS 23 KB. Same wave layout idea:
// wave w computes the 16x16 C-tile at cols w*16.
// MERGE: A = attention 4-way split-merge (sum of partials / sum(l)).
// RESID: adds Rf before store. SCALEQ unused here.
template <int RELU, int AF32, int OUT_F32, int OUT_BF16, int MERGE, int RESID>
__global__ __launch_bounds__(256) void gemm16(
    const void* __restrict__ Aptr, const float* __restrict__ pmp,
    const unsigned short* __restrict__ W, const float* __restrict__ bias,
    const float* __restrict__ Rf, float* __restrict__ Cf,
    unsigned short* __restrict__ Cb, int M, int N, int K) {
  __shared__ __align__(16) unsigned short As[2][16][72];
  __shared__ __align__(16) unsigned short Ws[2][64][72];
  const int tid = threadIdx.x;
  const int wid = tid >> 6, lane = tid & 63;
  const int ln = lane & 15, quad = lane >> 4;
  const int m0 = blockIdx.x * 16, n0 = blockIdx.y * 64;
  const int arow = tid >> 4, aseg = tid & 15;  // A: 16 threads/row, 4 elems
  const int wrow = tid >> 2, wseg = tid & 3;   // W: 4 threads/row, 16 elems
  const int KS = K >> 6;

  bf16x4 ra;
  float4 ra32;
  bf16x8 rwb0, rwb1;
  bf16x4 rp[4];
  float rl;

  auto load_tile = [&](int ks) {
    const int k0 = ks * 64;
    if (MERGE) {
      const int h = ks;  // K=512, 8 heads of 64: head index == K-step
      const int row = m0 + arow;
      rl = 0.f;
#pragma unroll
      for (int s = 0; s < 4; ++s) {
        const size_t b = (size_t)((s * 8 + h) * 2048 + row);
        rl += pmp[b];
        rp[s] = *(const bf16x4*)((const unsigned short*)Aptr + b * 64 + aseg * 4);
      }
    } else if (AF32) {
      ra32 = *(const float4*)((const float*)Aptr + (size_t)(m0 + arow) * K + k0 + aseg * 4);
    } else {
      ra = *(const bf16x4*)((const unsigned short*)Aptr +
                            (size_t)(m0 + arow) * K + k0 + aseg * 4);
    }
    const unsigned short* wp = W + (size_t)(n0 + wrow) * K + k0 + wseg * 16;
    rwb0 = *(const bf16x8*)wp;
    rwb1 = *(const bf16x8*)(wp + 8);
  };

  auto store_tile = [&](int buf) {
    if (MERGE) {
      float inv = 1.f / rl;
      float s0 = b2f((unsigned short)rp[0][0]) + b2f((unsigned short)rp[1][0]) +
                 b2f((unsigned short)rp[2][0]) + b2f((unsigned short)rp[3][0]);
      float s1 = b2f((unsigned short)rp[0][1]) + b2f((unsigned short)rp[1][1]) +
                 b2f((unsigned short)rp[2][1]) + b2f((unsigned short)rp[3][1]);
      float s2 = b2f((unsigned short)rp[0][2]) + b2f((unsigned short)rp[1][2]) +
                 b2f((unsigned short)rp[2][2]) + b2f((unsigned short)rp[3][2]);
      float s3 = b2f((unsigned short)rp[0][3]) + b2f((unsigned short)rp[1][3]) +
                 b2f((unsigned short)rp[2][3]) + b2f((unsigned short)rp[3][3]);
      unsigned short ta[4];
      *(ushort2*)&ta[0] = pk2b(inv * s0, inv * s1);
      *(ushort2*)&ta[2] = pk2b(inv * s2, inv * s3);
      *(bf16x4*)&As[buf][arow][aseg * 4] = *(const bf16x4*)&ta[0];
    } else if (AF32) {
      unsigned short ta[4];
      *(ushort2*)&ta[0] = pk2b(ra32.x, ra32.y);
      *(ushort2*)&ta[2] = pk2b(ra32.z, ra32.w);
      *(bf16x4*)&As[buf][arow][aseg * 4] = *(const bf16x4*)&ta[0];
    } else {
      *(bf16x4*)&As[buf][arow][aseg * 4] = ra;
    }
    *(bf16x8*)&Ws[buf][wrow][wseg * 16] = rwb0;
    *(bf16x8*)&Ws[buf][wrow][wseg * 16 + 8] = rwb1;
  };

  f32x4 acc = (f32x4){0.f, 0.f, 0.f, 0.f};

  load_tile(0);
  store_tile(0);
  __syncthreads();

#pragma unroll 1
  for (int ks = 0; ks < KS; ++ks) {
    const int cur = ks & 1;
    if (ks + 1 < KS) load_tile(ks + 1);
#pragma unroll
    for (int kc = 0; kc < 2; ++kc) {
      bf16x8 af = *(const bf16x8*)&As[cur][ln][kc * 32 + quad * 8];
      bf16x8 wf = *(const bf16x8*)&Ws[cur][wid * 16 + ln][kc * 32 + quad * 8];
      acc = __builtin_amdgcn_mfma_f32_16x16x32_bf16(af, wf, acc, 0, 0, 0);
    }
    if (ks + 1 < KS) store_tile(cur ^ 1);
    __syncthreads();
  }

  const int gm = m0 + quad * 4;
  const int gn = n0 + wid * 16 + ln;
  float bv = bias[gn];
#pragma unroll
  for (int r = 0; r < 4; ++r) {
    float v = acc[r] + bv;
    if (RELU) v = fmaxf(v, 0.f);
    if (RESID) v += Rf[(size_t)(gm + r) * N + gn];
    if (OUT_F32) Cf[(size_t)(gm + r) * N + gn] = v;
    if (OUT_BF16) Cb[(size_t)(gm + r) * N + gn] = f2b(v);
  }
}

// ============ Flash attention v9: key-split 4, single-buffer LDS ===========
// l = P @ ones via an extra MFMA (register-splat B, no LDS read, no epilogue
// shuffles). grid (32 q-tiles, 8 heads, 4 splits) = 1024 blocks; LDS 27.6 KB
// -> 4-5 resident blocks/CU. No-max softmax (q pre-scaled by 1/8 in qkv GEMM).
__global__ __launch_bounds__(256) void flash_attn9(
    const unsigned short* __restrict__ qkv, float* __restrict__ pm,
    unsigned short* __restrict__ po) {
  __shared__ __align__(16) unsigned short Ks[64][72];
  __shared__ __align__(16) unsigned short Vt[64][72];
  __shared__ __align__(16) unsigned short Ps[64][72];
  const int qt = blockIdx.x, h = blockIdx.y, sp = blockIdx.z;
  const int tid = threadIdx.x;
  const int wid = tid >> 6, lane = tid & 63;
  const int ln = lane & 15, quad = lane >> 4;
  const int wq0 = wid * 16;

  bf16x8 aq[2];
  {
    const unsigned short* qp =
        qkv + (size_t)(qt * 64 + wq0 + ln) * 1536 + h * 64 + quad * 8;
    aq[0] = *(const bf16x8*)qp;
    aq[1] = *(const bf16x8*)(qp + 32);
  }
  const bf16x8 ones = {0x3F80, 0x3F80, 0x3F80, 0x3F80,
                       0x3F80, 0x3F80, 0x3F80, 0x3F80};  // bf16 1.0 x8

  const int key = tid >> 2, seg = tid & 3;  // K staging
  bf16x8 rk0, rk1;
  unsigned short tv[16];

  auto load_kv = [&](int t) {
    const int g = sp * 8 + t;
    const unsigned short* kr =
        qkv + (size_t)(g * 64 + key) * 1536 + 512 + h * 64 + seg * 16;
    rk0 = *(const bf16x8*)kr;
    rk1 = *(const bf16x8*)(kr + 8);
#pragma unroll
    for (int j = 0; j < 16; ++j)
      tv[j] = qkv[(size_t)(g * 64 + wid * 16 + j) * 1536 + 1024 + h * 64 + lane];
  };
  auto store_kv = [&]() {
    *(bf16x8*)&Ks[key][seg * 16] = rk0;
    *(bf16x8*)&Ks[key][seg * 16 + 8] = rk1;
    *(bf16x8*)&Vt[lane][wid * 16] = *(const bf16x8*)&tv[0];
    *(bf16x8*)&Vt[lane][wid * 16 + 8] = *(const bf16x8*)&tv[8];
  };

  f32x4 acc_l = (f32x4){0.f, 0.f, 0.f, 0.f};
  f32x4 acc_o[4];
#pragma unroll
  for (int nt = 0; nt < 4; ++nt) acc_o[nt] = (f32x4){0.f, 0.f, 0.f, 0.f};

  load_kv(0);
  store_kv();
  __syncthreads();

#pragma unroll 1
  for (int t = 0; t < 8; ++t) {
    if (t + 1 < 8) load_kv(t + 1);  // global latency overlaps compute

    f32x4 s_acc[4];
#pragma unroll
    for (int nt = 0; nt < 4; ++nt) s_acc[nt] = (f32x4){0.f, 0.f, 0.f, 0.f};
#pragma unroll
    for (int nt = 0; nt < 4; ++nt) {
      bf16x8 kf0 = *(const bf16x8*)&Ks[nt * 16 + ln][quad * 8];
      bf16x8 kf1 = *(const bf16x8*)&Ks[nt * 16 + ln][32 + quad * 8];
      s_acc[nt] = __builtin_amdgcn_mfma_f32_16x16x32_bf16(aq[0], kf0, s_acc[nt], 0, 0, 0);
      s_acc[nt] = __builtin_amdgcn_mfma_f32_16x16x32_bf16(aq[1], kf1, s_acc[nt], 0, 0, 0);
    }

    // p = exp(s) (q pre-scaled); P -> LDS (wave-local rows)
#pragma unroll
    for (int nt = 0; nt < 4; ++nt) {
#pragma unroll
      for (int r = 0; r < 4; ++r) {
        float p = __expf(s_acc[nt][r]);
        Ps[wq0 + quad * 4 + r][nt * 16 + ln] = f2b(p);
      }
    }

#pragma unroll
    for (int kc = 0; kc < 2; ++kc) {
      bf16x8 pf = *(const bf16x8*)&Ps[wq0 + ln][kc * 32 + quad * 8];
      acc_l = __builtin_amdgcn_mfma_f32_16x16x32_bf16(pf, ones, acc_l, 0, 0, 0);
#pragma unroll
      for (int nt = 0; nt < 4; ++nt) {
        bf16x8 vf = *(const bf16x8*)&Vt[nt * 16 + ln][kc * 32 + quad * 8];
        acc_o[nt] = __builtin_amdgcn_mfma_f32_16x16x32_bf16(pf, vf, acc_o[nt], 0, 0, 0);
      }
    }
    __syncthreads();  // all reads of Ks/Vt complete before overwrite
    if (t + 1 < 8) {
      store_kv();
      __syncthreads();
    }
  }

  const size_t base = (size_t)((sp * 8 + h) * 2048 + qt * 64);
#pragma unroll
  for (int r = 0; r < 4; ++r) {
    const size_t row = base + wq0 + quad * 4 + r;
    if (ln == 0) pm[row] = acc_l[r];
#pragma unroll
    for (int nt = 0; nt < 4; ++nt)
      po[row * 64 + nt * 16 + ln] = f2b(acc_o[nt][r]);
  }
}

// ============ Row-wise kernels (one wave per row of 2048) ==================
__global__ __launch_bounds__(256) void inorm512(float* __restrict__ dst,
                                                unsigned short* __restrict__ dstb,
                                                const float* __restrict__ src) {
  const int row = blockIdx.x * 4 + (threadIdx.x >> 6);
  const int lane = threadIdx.x & 63;
  const float4* s = (const float4*)(src + (size_t)row * 512);
  float4 a = s[lane], b = s[lane + 64];
  float sum = a.x + a.y + a.z + a.w + b.x + b.y + b.z + b.w;
  float mean = wave_sum(sum) * (1.f / 512.f);
  float vs = (a.x - mean) * (a.x - mean) + (a.y - mean) * (a.y - mean) +
             (a.z - mean) * (a.z - mean) + (a.w - mean) * (a.w - mean) +
             (b.x - mean) * (b.x - mean) + (b.y - mean) * (b.y - mean) +
             (b.z - mean) * (b.z - mean) + (b.w - mean) * (b.w - mean);
  float rs = rsqrtf(wave_sum(vs) * (1.f / 512.f) + EPS);
  float4 oa, obv;
  oa.x = (a.x - mean) * rs; oa.y = (a.y - mean) * rs;
  oa.z = (a.z - mean) * rs; oa.w = (a.w - mean) * rs;
  obv.x = (b.x - mean) * rs; obv.y = (b.y - mean) * rs;
  obv.z = (b.z - mean) * rs; obv.w = (b.w - mean) * rs;
  float4* d = (float4*)(dst + (size_t)row * 512);
  d[lane] = oa; d[lane + 64] = obv;
  unsigned short* db = dstb + (size_t)row * 512;
  *(ushort2*)&db[lane * 4] = pk2b(oa.x, oa.y);
  *(ushort2*)&db[lane * 4 + 2] = pk2b(oa.z, oa.w);
  *(ushort2*)&db[256 + lane * 4] = pk2b(obv.x, obv.y);
  *(ushort2*)&db[256 + lane * 4 + 2] = pk2b(obv.z, obv.w);
}

// LN over rows of src (already residual-summed); writes f32 + bf16
__global__ __launch_bounds__(256) void ln_res2(float* __restrict__ dst,
                                               unsigned short* __restrict__ dstb,
                                               const float* __restrict__ src,
                                               const float* __restrict__ w,
                                               const float* __restrict__ bb) {
  const int row = blockIdx.x * 4 + (threadIdx.x >> 6);
  const int lane = threadIdx.x & 63;
  const float4* xs = (const float4*)(src + (size_t)row * 512);
  float4 a = xs[lane], b = xs[lane + 64];
  float sum = a.x + a.y + a.z + a.w + b.x + b.y + b.z + b.w;
  float mean = wave_sum(sum) * (1.f / 512.f);
  float vs = (a.x - mean) * (a.x - mean) + (a.y - mean) * (a.y - mean) +
             (a.z - mean) * (a.z - mean) + (a.w - mean) * (a.w - mean) +
             (b.x - mean) * (b.x - mean) + (b.y - mean) * (b.y - mean) +
             (b.z - mean) * (b.z - mean) + (b.w - mean) * (b.w - mean);
  float rs = rsqrtf(wave_sum(vs) * (1.f / 512.f) + EPS);
  float4 wa = ((const float4*)w)[lane], wb = ((const float4*)w)[lane + 64];
  float4 ba = ((const float4*)bb)[lane], bbv = ((const float4*)bb)[lane + 64];
  float4 oa, ob2;
  oa.x = (a.x - mean) * rs * wa.x + ba.x; oa.y = (a.y - mean) * rs * wa.y + ba.y;
  oa.z = (a.z - mean) * rs * wa.z + ba.z; oa.w = (a.w - mean) * rs * wa.w + ba.w;
  ob2.x = (b.x - mean) * rs * wb.x + bbv.x; ob2.y = (b.y - mean) * rs * wb.y + bbv.y;
  ob2.z = (b.z - mean) * rs * wb.z + bbv.z; ob2.w = (b.w - mean) * rs * wb.w + bbv.w;
  float4* d = (float4*)(dst + (size_t)row * 512);
  d[lane] = oa; d[lane + 64] = ob2;
  unsigned short* dbp = dstb + (size_t)row * 512;
  *(ushort2*)&dbp[lane * 4] = pk2b(oa.x, oa.y);
  *(ushort2*)&dbp[lane * 4 + 2] = pk2b(oa.z, oa.w);
  *(ushort2*)&dbp[256 + lane * 4] = pk2b(ob2.x, ob2.y);
  *(ushort2*)&dbp[256 + lane * 4 + 2] = pk2b(ob2.z, ob2.w);
}

__global__ __launch_bounds__(256) void add_inorm(float* __restrict__ feat,
                                                 unsigned short* __restrict__ featb,
                                                 const float* __restrict__ feat0) {
  const int row = blockIdx.x * 4 + (threadIdx.x >> 6);
  const int lane = threadIdx.x & 63;
  float4* f = (float4*)(feat + (size_t)row * 512);
  const float4* f0 = (const float4*)(feat0 + (size_t)row * 512);
  float4 a = f[lane], b = f[lane + 64];
  float sum = a.x + a.y + a.z + a.w + b.x + b.y + b.z + b.w;
  float mean = wave_sum(sum) * (1.f / 512.f);
  float vs = (a.x - mean) * (a.x - mean) + (a.y - mean) * (a.y - mean) +
             (a.z - mean) * (a.z - mean) + (a.w - mean) * (a.w - mean) +
             (b.x - mean) * (b.x - mean) + (b.y - mean) * (b.y - mean) +
             (b.z - mean) * (b.z - mean) + (b.w - mean) * (b.w - mean);
  float rs = rsqrtf(wave_sum(vs) * (1.f / 512.f) + EPS);
  float4 za = f0[lane], zb = f0[lane + 64];
  float4 oa, ob2;
  oa.x = za.x + (a.x - mean) * rs; oa.y = za.y + (a.y - mean) * rs;
  oa.z = za.z + (a.z - mean) * rs; oa.w = za.w + (a.w - mean) * rs;
  ob2.x = zb.x + (b.x - mean) * rs; ob2.y = zb.y + (b.y - mean) * rs;
  ob2.z = zb.z + (b.z - mean) * rs; ob2.w = zb.w + (b.w - mean) * rs;
  f[lane] = oa; f[lane + 64] = ob2;
  unsigned short* dbp = featb + (size_t)row * 512;
  *(ushort2*)&dbp[lane * 4] = pk2b(oa.x, oa.y);
  *(ushort2*)&dbp[lane * 4 + 2] = pk2b(oa.z, oa.w);
  *(ushort2*)&dbp[256 + lane * 4] = pk2b(ob2.x, ob2.y);
  *(ushort2*)&dbp[256 + lane * 4 + 2] = pk2b(ob2.z, ob2.w);
}

// dist with fused inorm128: one wave per row
__global__ __launch_bounds__(256) void dist2(const float* __restrict__ fq,
                                             const float* __restrict__ hi,
                                             const float* __restrict__ ne,
                                             float* __restrict__ out) {
  const int row = blockIdx.x * 4 + (threadIdx.x >> 6);
  const int lane = threadIdx.x & 63;
  float f0 = fq[(size_t)row * 128 + lane];
  float f1 = fq[(size_t)row * 128 + 64 + lane];
  float mean = wave_sum(f0 + f1) * (1.f / 128.f);
  float vs = (f0 - mean) * (f0 - mean) + (f1 - mean) * (f1 - mean);
  float rs = rsqrtf(wave_sum(vs) * (1.f / 128.f) + EPS);
  f0 = (f0 - mean) * rs;
  f1 = (f1 - mean) * rs;
  float mp = 1e30f, mn = 1e30f;
  for (int p = 0; p < 40; ++p) {
    float h0 = hi[p * 128 + lane], h1 = hi[p * 128 + 64 + lane];
    float d0 = f0 - h0, d1 = f1 - h1;
    float d2 = wave_sum(d0 * d0 + d1 * d1);
    mp = fminf(mp, d2);
    float n0 = ne[p * 128 + lane], n1 = ne[p * 128 + 64 + lane];
    d0 = f0 - n0; d1 = f1 - n1;
    d2 = wave_sum(d0 * d0 + d1 * d1);
    mn = fminf(mn, d2);
  }
  if (lane == 0) {
    out[row * 2 + 0] = -sqrtf(mn);
    out[row * 2 + 1] = -sqrtf(mp);
  }
}

extern "C" void kernel_launch(void* const* d_in, const int* in_sizes, int n_in,
                              void* d_out, int out_size, void* d_ws, size_t ws_size,
                              hipStream_t stream) {
  const float* x        = (const float*)d_in[0];
  const float* reduce_w = (const float*)d_in[1];
  const float* reduce_b = (const float*)d_in[2];
  const float* in_w     = (const float*)d_in[3];
  const float* in_b     = (const float*)d_in[4];
  const float* out_w    = (const float*)d_in[5];
  const float* out_b    = (const float*)d_in[6];
  const float* ff1_w    = (const float*)d_in[7];
  const float* ff1_b    = (const float*)d_in[8];
  const float* ff2_w    = (const float*)d_in[9];
  const float* ff2_b    = (const float*)d_in[10];
  const float* ln1_w    = (const float*)d_in[11];
  const float* ln1_b    = (const float*)d_in[12];
  const float* ln2_w    = (const float*)d_in[13];
  const float* ln2_b    = (const float*)d_in[14];
  const float* mlp_w1   = (const float*)d_in[15];
  const float* mlp_b1   = (const float*)d_in[16];
  const float* mlp_w2   = (const float*)d_in[17];
  const float* mlp_b2   = (const float*)d_in[18];
  const float* mlp_w3   = (const float*)d_in[19];
  const float* mlp_b3   = (const float*)d_in[20];
  const float* hi       = (const float*)d_in[21];
  const float* ne       = (const float*)d_in[22];
  float* out = (float*)d_out;
  float* ws = (float*)d_ws;

  const size_t MD = (size_t)2048 * 512;  // 1M elems
  float* feat0_f = ws;                // MD
  float* feat_f  = ws + MD;           // MD
  float* tmp_f   = ws + 2 * MD;       // MD
  float* pm      = ws + 3 * MD;       // 4*8*2048 = 65536 f32
  unsigned short* u = (unsigned short*)(ws + 3 * MD + 65536);
  unsigned short* qkv_b   = u;            // 3*MD
  unsigned short* feat0_b = u + 3 * MD;   // MD
  unsigned short* feat_b  = u + 4 * MD;   // MD
  unsigned short* relu_b  = u + 5 * MD;   // MD
  unsigned short* po_b    = u + 6 * MD;   // 4*8*2048*64 = 4*MD
  unsigned short* relu2_b = qkv_b;        // alias: attention done by then
  float* featq_f = tmp_f;

  // bf16 weight region
  unsigned short* wb = u + 10 * MD;
  unsigned short* reduce_wb = wb;                   // 393216
  unsigned short* in_wb     = wb + 393216;          // 2359296
  unsigned short* out_wb    = in_wb + 2359296;      // 786432
  unsigned short* ff1_wb    = out_wb + 786432;      // 786432
  unsigned short* ff2_wb    = ff1_wb + 786432;      // 786432
  unsigned short* mlp_w1b   = ff2_wb + 786432;      // 262144
  unsigned short* mlp_w2b   = mlp_w1b + 262144;     // 262144
  unsigned short* mlp_w3b   = mlp_w2b + 262144;     // 65536

  dim3 blk(256);
  WConvArgs wa;
  wa.src[0] = reduce_w; wa.dst[0] = reduce_wb; wa.n[0] = 393216;
  wa.src[1] = in_w;     wa.dst[1] = in_wb;     wa.n[1] = 2359296;
  wa.src[2] = out_w;    wa.dst[2] = out_wb;    wa.n[2] = 786432;
  wa.src[3] = ff1_w;    wa.dst[3] = ff1_wb;    wa.n[3] = 786432;
  wa.src[4] = ff2_w;    wa.dst[4] = ff2_wb;    wa.n[4] = 786432;
  wa.src[5] = mlp_w1;   wa.dst[5] = mlp_w1b;   wa.n[5] = 262144;
  wa.src[6] = mlp_w2;   wa.dst[6] = mlp_w2b;   wa.n[6] = 262144;
  wa.src[7] = mlp_w3;   wa.dst[7] = mlp_w3b;   wa.n[7] = 65536;
  conv_w<<<dim3(2304, 8), blk, 0, stream>>>(wa);

  // reduce: fp32 A path, 16-row tiles -> 1024 blocks
  gemm16<0, 1, 1, 0, 0, 0><<<dim3(128, 8), blk, 0, stream>>>(
      x, nullptr, reduce_wb, reduce_b, nullptr, feat0_f, nullptr, 2048, 512, 768);
  inorm512<<<512, blk, 0, stream>>>(feat0_f, feat0_b, feat0_f);

  for (int i = 0; i < 3; ++i) {
    const float* fin_f = (i == 0) ? feat0_f : feat_f;
    const unsigned short* fin_b = (i == 0) ? feat0_b : feat_b;
    gemm32<1><<<dim3(64, 24), blk, 0, stream>>>(
        fin_b, in_wb + (size_t)i * 1536 * 512, in_b + i * 1536, qkv_b,
        2048, 1536, 512);
    flash_attn9<<<dim3(32, 8, 4), blk, 0, stream>>>(qkv_b, pm, po_b);
    gemm16<0, 0, 1, 0, 1, 1><<<dim3(128, 8), blk, 0, stream>>>(
        po_b, pm, out_wb + (size_t)i * 512 * 512, out_b + i * 512,
        fin_f, tmp_f, nullptr, 2048, 512, 512);
    ln_res2<<<512, blk, 0, stream>>>(feat_f, feat_b, tmp_f,
                                     ln1_w + i * 512, ln1_b + i * 512);
    gemm16<1, 0, 0, 1, 0, 0><<<dim3(128, 8), blk, 0, stream>>>(
        feat_b, nullptr, ff1_wb + (size_t)i * 512 * 512, ff1_b + i * 512,
        nullptr, nullptr, relu_b, 2048, 512, 512);
    gemm16<0, 0, 1, 0, 0, 1><<<dim3(128, 8), blk, 0, stream>>>(
        relu_b, nullptr, ff2_wb + (size_t)i * 512 * 512, ff2_b + i * 512,
        feat_f, tmp_f, nullptr, 2048, 512, 512);
    ln_res2<<<512, blk, 0, stream>>>(feat_f, feat_b, tmp_f,
                                     ln2_w + i * 512, ln2_b + i * 512);
  }

  add_inorm<<<512, blk, 0, stream>>>(feat_f, feat_b, feat0_f);
  gemm16<1, 0, 0, 1, 0, 0><<<dim3(128, 8), blk, 0, stream>>>(
      feat_b, nullptr, mlp_w1b, mlp_b1, nullptr, nullptr, relu_b, 2048, 512, 512);
  gemm16<1, 0, 0, 1, 0, 0><<<dim3(128, 8), blk, 0, stream>>>(
      relu_b, nullptr, mlp_w2b, mlp_b2, nullptr, nullptr, relu2_b, 2048, 512, 512);
  gemm16<0, 0, 1, 0, 0, 0><<<dim3(128, 2), blk, 0, stream>>>(
      relu2_b, nullptr, mlp_w3b, mlp_b3, nullptr, featq_f, nullptr, 2048, 128, 512);
  dist2<<<512, blk, 0, stream>>>(featq_f, hi, ne, out);
}

// Round 12
// 367.892 us; speedup vs baseline: 1.0181x; 1.0181x over previous
//
#include <hip/hip_runtime.h>
#include <hip/hip_bf16.h>
#include <math.h>
#include <cstddef>

#define EPS 1e-5f

typedef __attribute__((ext_vector_type(8))) short bf16x8;
typedef __attribute__((ext_vector_type(4))) float f32x4;

__device__ __forceinline__ float wave_sum(float v) {
#pragma unroll
  for (int o = 32; o > 0; o >>= 1) v += __shfl_xor(v, o, 64);
  return v;
}

// fp32 -> bf16 bits, round-to-nearest-even (finite inputs only)
__device__ __forceinline__ unsigned short f2b(float f) {
  union { float f; unsigned int u; } v; v.f = f;
  unsigned int r = (v.u + 0x7FFFu + ((v.u >> 16) & 1u)) >> 16;
  return (unsigned short)r;
}
__device__ __forceinline__ float b2f(unsigned short u) {
  union { unsigned int u; float f; } v; v.u = ((unsigned int)u) << 16;
  return v.f;
}
// packed pair convert (RNE) — lets the compiler use gfx950 packed cvt
__device__ __forceinline__ ushort2 pk2b(float a, float b) {
  __hip_bfloat162 h = __float22bfloat162_rn(make_float2(a, b));
  union { __hip_bfloat162 h; ushort2 u; } v;
  v.h = h;
  return v.u;
}

// ============ Weight pre-conversion: fp32 -> bf16, 8 arrays in one launch ==
struct WConvArgs {
  const float* src[8];
  unsigned short* dst[8];
  int n[8];
};
__global__ __launch_bounds__(256) void conv_w(WConvArgs a) {
  const int arr = blockIdx.y;
  const int i = (blockIdx.x * 256 + threadIdx.x) * 4;
  if (i >= a.n[arr]) return;
  const float4 f = *(const float4*)(a.src[arr] + i);
  unsigned short* d = a.dst[arr] + i;
  *(ushort2*)d = pk2b(f.x, f.y);
  *(ushort2*)(d + 2) = pk2b(f.z, f.w);
}

// ============ MFMA GEMM: C[M,N] = A[M,K] @ W[N,K]^T + bias =================
// W pre-converted bf16. 32x64 tile, 4 waves. Double-buffered LDS, register
// prefetch, 1 barrier/K-step.  (r10 best-known configuration.)
// MERGE: A = attention split-merge: sum of 4 unnormalized partials / sum(l).
// RESID: epilogue adds Rf (residual) before store.
// SCALEQ: multiply columns [0,512) by 0.125 (q scale for attention).
template <int RELU, int AF32, int OUT_F32, int OUT_BF16, int MERGE, int RESID,
          int SCALEQ>
__global__ __launch_bounds__(256) void gemm32(
    const void* __restrict__ Aptr, const float* __restrict__ pmp,
    const unsigned short* __restrict__ W, const float* __restrict__ bias,
    const float* __restrict__ Rf, float* __restrict__ Cf,
    unsigned short* __restrict__ Cb, int M, int N, int K) {
  __shared__ __align__(16) unsigned short As[2][32][72];
  __shared__ __align__(16) unsigned short Ws[2][64][72];
  const int tid = threadIdx.x;
  const int wid = tid >> 6, lane = tid & 63;
  const int ln = lane & 15, quad = lane >> 4;
  const int m0 = blockIdx.x * 32, n0 = blockIdx.y * 64;
  const int arow = tid >> 3, aseg = tid & 7;   // A: 8 threads/row, 8 elems
  const int wrow = tid >> 2, wseg = tid & 3;   // W: 4 threads/row, 16 elems
  const int KS = K >> 6;

  bf16x8 ra;
  float4 ra32[2];
  bf16x8 rwb0, rwb1;
  bf16x8 rp[4];
  float rl;

  auto load_tile = [&](int ks) {
    const int k0 = ks * 64;
    if (MERGE) {
      const int h = ks;  // K=512, 8 heads of 64: head index == K-step
      const int row = m0 + arow;
      rl = 0.f;
#pragma unroll
      for (int s = 0; s < 4; ++s) {
        const size_t b = (size_t)((s * 8 + h) * 2048 + row);
        rl += pmp[b];
        rp[s] = *(const bf16x8*)((const unsigned short*)Aptr + b * 64 + aseg * 8);
      }
    } else if (AF32) {
      const float* ap = (const float*)Aptr + (size_t)(m0 + arow) * K + k0 + aseg * 8;
      ra32[0] = *(const float4*)ap;
      ra32[1] = *(const float4*)(ap + 4);
    } else {
      ra = *(const bf16x8*)((const unsigned short*)Aptr +
                            (size_t)(m0 + arow) * K + k0 + aseg * 8);
    }
    const unsigned short* wp = W + (size_t)(n0 + wrow) * K + k0 + wseg * 16;
    rwb0 = *(const bf16x8*)wp;
    rwb1 = *(const bf16x8*)(wp + 8);
  };

  auto store_tile = [&](int buf) {
    if (MERGE) {
      float inv = 1.f / rl;
      unsigned short ta[8];
#pragma unroll
      for (int j = 0; j < 8; j += 2) {
        float s0 = b2f((unsigned short)rp[0][j]) + b2f((unsigned short)rp[1][j]) +
                   b2f((unsigned short)rp[2][j]) + b2f((unsigned short)rp[3][j]);
        float s1 = b2f((unsigned short)rp[0][j + 1]) + b2f((unsigned short)rp[1][j + 1]) +
                   b2f((unsigned short)rp[2][j + 1]) + b2f((unsigned short)rp[3][j + 1]);
        *(ushort2*)&ta[j] = pk2b(inv * s0, inv * s1);
      }
      *(bf16x8*)&As[buf][arow][aseg * 8] = *(const bf16x8*)&ta[0];
    } else if (AF32) {
      unsigned short ta[8];
      *(ushort2*)&ta[0] = pk2b(ra32[0].x, ra32[0].y);
      *(ushort2*)&ta[2] = pk2b(ra32[0].z, ra32[0].w);
      *(ushort2*)&ta[4] = pk2b(ra32[1].x, ra32[1].y);
      *(ushort2*)&ta[6] = pk2b(ra32[1].z, ra32[1].w);
      *(bf16x8*)&As[buf][arow][aseg * 8] = *(const bf16x8*)&ta[0];
    } else {
      *(bf16x8*)&As[buf][arow][aseg * 8] = ra;
    }
    *(bf16x8*)&Ws[buf][wrow][wseg * 16] = rwb0;
    *(bf16x8*)&Ws[buf][wrow][wseg * 16 + 8] = rwb1;
  };

  f32x4 acc[2];
  acc[0] = (f32x4){0.f, 0.f, 0.f, 0.f};
  acc[1] = (f32x4){0.f, 0.f, 0.f, 0.f};

  const int mrow = (wid & 1) * 16, nh = wid >> 1;

  load_tile(0);
  store_tile(0);
  __syncthreads();

#pragma unroll 1
  for (int ks = 0; ks < KS; ++ks) {
    const int cur = ks & 1;
    if (ks + 1 < KS) load_tile(ks + 1);
#pragma unroll
    for (int kc = 0; kc < 2; ++kc) {
      bf16x8 af = *(const bf16x8*)&As[cur][mrow + ln][kc * 32 + quad * 8];
#pragma unroll
      for (int nt = 0; nt < 2; ++nt) {
        bf16x8 wf = *(const bf16x8*)&Ws[cur][nh * 32 + nt * 16 + ln][kc * 32 + quad * 8];
        acc[nt] = __builtin_amdgcn_mfma_f32_16x16x32_bf16(af, wf, acc[nt], 0, 0, 0);
      }
    }
    if (ks + 1 < KS) store_tile(cur ^ 1);
    __syncthreads();
  }

  const int gm = m0 + mrow + quad * 4;
  const float qs = (SCALEQ && n0 < 512) ? 0.125f : 1.f;
#pragma unroll
  for (int nt = 0; nt < 2; ++nt) {
    const int gn = n0 + nh * 32 + nt * 16 + ln;
    float bv = bias[gn];
#pragma unroll
    for (int r = 0; r < 4; ++r) {
      float v = acc[nt][r] + bv;
      if (SCALEQ) v *= qs;
      if (RELU) v = fmaxf(v, 0.f);
      if (RESID) v += Rf[(size_t)(gm + r) * N + gn];
      if (OUT_F32) Cf[(size_t)(gm + r) * N + gn] = v;
      if (OUT_BF16) Cb[(size_t)(gm + r) * N + gn] = f2b(v);
    }
  }
}

// ============ Flash attention v9: key-split 4, single-buffer LDS ===========
// l = P @ ones via an extra MFMA (register-splat B, no LDS read, no epilogue
// shuffles). grid (32 q-tiles, 8 heads, 4 splits) = 1024 blocks; LDS 27.6 KB
// -> 4-5 resident blocks/CU. No-max softmax (q pre-scaled by 1/8 in qkv GEMM).
__global__ __launch_bounds__(256) void flash_attn9(
    const unsigned short* __restrict__ qkv, float* __restrict__ pm,
    unsigned short* __restrict__ po) {
  __shared__ __align__(16) unsigned short Ks[64][72];
  __shared__ __align__(16) unsigned short Vt[64][72];
  __shared__ __align__(16) unsigned short Ps[64][72];
  const int qt = blockIdx.x, h = blockIdx.y, sp = blockIdx.z;
  const int tid = threadIdx.x;
  const int wid = tid >> 6, lane = tid & 63;
  const int ln = lane & 15, quad = lane >> 4;
  const int wq0 = wid * 16;

  bf16x8 aq[2];
  {
    const unsigned short* qp =
        qkv + (size_t)(qt * 64 + wq0 + ln) * 1536 + h * 64 + quad * 8;
    aq[0] = *(const bf16x8*)qp;
    aq[1] = *(const bf16x8*)(qp + 32);
  }
  const bf16x8 ones = {0x3F80, 0x3F80, 0x3F80, 0x3F80,
                       0x3F80, 0x3F80, 0x3F80, 0x3F80};  // bf16 1.0 x8

  const int key = tid >> 2, seg = tid & 3;  // K staging
  bf16x8 rk0, rk1;
  unsigned short tv[16];

  auto load_kv = [&](int t) {
    const int g = sp * 8 + t;
    const unsigned short* kr =
        qkv + (size_t)(g * 64 + key) * 1536 + 512 + h * 64 + seg * 16;
    rk0 = *(const bf16x8*)kr;
    rk1 = *(const bf16x8*)(kr + 8);
#pragma unroll
    for (int j = 0; j < 16; ++j)
      tv[j] = qkv[(size_t)(g * 64 + wid * 16 + j) * 1536 + 1024 + h * 64 + lane];
  };
  auto store_kv = [&]() {
    *(bf16x8*)&Ks[key][seg * 16] = rk0;
    *(bf16x8*)&Ks[key][seg * 16 + 8] = rk1;
    *(bf16x8*)&Vt[lane][wid * 16] = *(const bf16x8*)&tv[0];
    *(bf16x8*)&Vt[lane][wid * 16 + 8] = *(const bf16x8*)&tv[8];
  };

  f32x4 acc_l = (f32x4){0.f, 0.f, 0.f, 0.f};
  f32x4 acc_o[4];
#pragma unroll
  for (int nt = 0; nt < 4; ++nt) acc_o[nt] = (f32x4){0.f, 0.f, 0.f, 0.f};

  load_kv(0);
  store_kv();
  __syncthreads();

#pragma unroll 1
  for (int t = 0; t < 8; ++t) {
    if (t + 1 < 8) load_kv(t + 1);  // global latency overlaps compute

    f32x4 s_acc[4];
#pragma unroll
    for (int nt = 0; nt < 4; ++nt) s_acc[nt] = (f32x4){0.f, 0.f, 0.f, 0.f};
#pragma unroll
    for (int nt = 0; nt < 4; ++nt) {
      bf16x8 kf0 = *(const bf16x8*)&Ks[nt * 16 + ln][quad * 8];
      bf16x8 kf1 = *(const bf16x8*)&Ks[nt * 16 + ln][32 + quad * 8];
      s_acc[nt] = __builtin_amdgcn_mfma_f32_16x16x32_bf16(aq[0], kf0, s_acc[nt], 0, 0, 0);
      s_acc[nt] = __builtin_amdgcn_mfma_f32_16x16x32_bf16(aq[1], kf1, s_acc[nt], 0, 0, 0);
    }

    // p = exp(s) (q pre-scaled); P -> LDS (wave-local rows)
#pragma unroll
    for (int nt = 0; nt < 4; ++nt) {
#pragma unroll
      for (int r = 0; r < 4; ++r) {
        float p = __expf(s_acc[nt][r]);
        Ps[wq0 + quad * 4 + r][nt * 16 + ln] = f2b(p);
      }
    }

#pragma unroll
    for (int kc = 0; kc < 2; ++kc) {
      bf16x8 pf = *(const bf16x8*)&Ps[wq0 + ln][kc * 32 + quad * 8];
      acc_l = __builtin_amdgcn_mfma_f32_16x16x32_bf16(pf, ones, acc_l, 0, 0, 0);
#pragma unroll
      for (int nt = 0; nt < 4; ++nt) {
        bf16x8 vf = *(const bf16x8*)&Vt[nt * 16 + ln][kc * 32 + quad * 8];
        acc_o[nt] = __builtin_amdgcn_mfma_f32_16x16x32_bf16(pf, vf, acc_o[nt], 0, 0, 0);
      }
    }
    __syncthreads();  // all reads of Ks/Vt complete before overwrite
    if (t + 1 < 8) {
      store_kv();
      __syncthreads();
    }
  }

  const size_t base = (size_t)((sp * 8 + h) * 2048 + qt * 64);
#pragma unroll
  for (int r = 0; r < 4; ++r) {
    const size_t row = base + wq0 + quad * 4 + r;
    if (ln == 0) pm[row] = acc_l[r];
#pragma unroll
    for (int nt = 0; nt < 4; ++nt)
      po[row * 64 + nt * 16 + ln] = f2b(acc_o[nt][r]);
  }
}

// ============ Row-wise kernels (one wave per row of 2048) ==================
__global__ __launch_bounds__(256) void inorm512(float* __restrict__ dst,
                                                unsigned short* __restrict__ dstb,
                                                const float* __restrict__ src) {
  const int row = blockIdx.x * 4 + (threadIdx.x >> 6);
  const int lane = threadIdx.x & 63;
  const float4* s = (const float4*)(src + (size_t)row * 512);
  float4 a = s[lane], b = s[lane + 64];
  float sum = a.x + a.y + a.z + a.w + b.x + b.y + b.z + b.w;
  float mean = wave_sum(sum) * (1.f / 512.f);
  float vs = (a.x - mean) * (a.x - mean) + (a.y - mean) * (a.y - mean) +
             (a.z - mean) * (a.z - mean) + (a.w - mean) * (a.w - mean) +
             (b.x - mean) * (b.x - mean) + (b.y - mean) * (b.y - mean) +
             (b.z - mean) * (b.z - mean) + (b.w - mean) * (b.w - mean);
  float rs = rsqrtf(wave_sum(vs) * (1.f / 512.f) + EPS);
  float4 oa, obv;
  oa.x = (a.x - mean) * rs; oa.y = (a.y - mean) * rs;
  oa.z = (a.z - mean) * rs; oa.w = (a.w - mean) * rs;
  obv.x = (b.x - mean) * rs; obv.y = (b.y - mean) * rs;
  obv.z = (b.z - mean) * rs; obv.w = (b.w - mean) * rs;
  float4* d = (float4*)(dst + (size_t)row * 512);
  d[lane] = oa; d[lane + 64] = obv;
  unsigned short* db = dstb + (size_t)row * 512;
  *(ushort2*)&db[lane * 4] = pk2b(oa.x, oa.y);
  *(ushort2*)&db[lane * 4 + 2] = pk2b(oa.z, oa.w);
  *(ushort2*)&db[256 + lane * 4] = pk2b(obv.x, obv.y);
  *(ushort2*)&db[256 + lane * 4 + 2] = pk2b(obv.z, obv.w);
}

// LN over rows of src (already residual-summed); writes f32 + bf16
__global__ __launch_bounds__(256) void ln_res2(float* __restrict__ dst,
                                               unsigned short* __restrict__ dstb,
                                               const float* __restrict__ src,
                                               const float* __restrict__ w,
                                               const float* __restrict__ bb) {
  const int row = blockIdx.x * 4 + (threadIdx.x >> 6);
  const int lane = threadIdx.x & 63;
  const float4* xs = (const float4*)(src + (size_t)row * 512);
  float4 a = xs[lane], b = xs[lane + 64];
  float sum = a.x + a.y + a.z + a.w + b.x + b.y + b.z + b.w;
  float mean = wave_sum(sum) * (1.f / 512.f);
  float vs = (a.x - mean) * (a.x - mean) + (a.y - mean) * (a.y - mean) +
             (a.z - mean) * (a.z - mean) + (a.w - mean) * (a.w - mean) +
             (b.x - mean) * (b.x - mean) + (b.y - mean) * (b.y - mean) +
             (b.z - mean) * (b.z - mean) + (b.w - mean) * (b.w - mean);
  float rs = rsqrtf(wave_sum(vs) * (1.f / 512.f) + EPS);
  float4 wa = ((const float4*)w)[lane], wb = ((const float4*)w)[lane + 64];
  float4 ba = ((const float4*)bb)[lane], bbv = ((const float4*)bb)[lane + 64];
  float4 oa, ob2;
  oa.x = (a.x - mean) * rs * wa.x + ba.x; oa.y = (a.y - mean) * rs * wa.y + ba.y;
  oa.z = (a.z - mean) * rs * wa.z + ba.z; oa.w = (a.w - mean) * rs * wa.w + ba.w;
  ob2.x = (b.x - mean) * rs * wb.x + bbv.x; ob2.y = (b.y - mean) * rs * wb.y + bbv.y;
  ob2.z = (b.z - mean) * rs * wb.z + bbv.z; ob2.w = (b.w - mean) * rs * wb.w + bbv.w;
  float4* d = (float4*)(dst + (size_t)row * 512);
  d[lane] = oa; d[lane + 64] = ob2;
  unsigned short* dbp = dstb + (size_t)row * 512;
  *(ushort2*)&dbp[lane * 4] = pk2b(oa.x, oa.y);
  *(ushort2*)&dbp[lane * 4 + 2] = pk2b(oa.z, oa.w);
  *(ushort2*)&dbp[256 + lane * 4] = pk2b(ob2.x, ob2.y);
  *(ushort2*)&dbp[256 + lane * 4 + 2] = pk2b(ob2.z, ob2.w);
}

__global__ __launch_bounds__(256) void add_inorm(float* __restrict__ feat,
                                                 unsigned short* __restrict__ featb,
                                                 const float* __restrict__ feat0) {
  const int row = blockIdx.x * 4 + (threadIdx.x >> 6);
  const int lane = threadIdx.x & 63;
  float4* f = (float4*)(feat + (size_t)row * 512);
  const float4* f0 = (const float4*)(feat0 + (size_t)row * 512);
  float4 a = f[lane], b = f[lane + 64];
  float sum = a.x + a.y + a.z + a.w + b.x + b.y + b.z + b.w;
  float mean = wave_sum(sum) * (1.f / 512.f);
  float vs = (a.x - mean) * (a.x - mean) + (a.y - mean) * (a.y - mean) +
             (a.z - mean) * (a.z - mean) + (a.w - mean) * (a.w - mean) +
             (b.x - mean) * (b.x - mean) + (b.y - mean) * (b.y - mean) +
             (b.z - mean) * (b.z - mean) + (b.w - mean) * (b.w - mean);
  float rs = rsqrtf(wave_sum(vs) * (1.f / 512.f) + EPS);
  float4 za = f0[lane], zb = f0[lane + 64];
  float4 oa, ob2;
  oa.x = za.x + (a.x - mean) * rs; oa.y = za.y + (a.y - mean) * rs;
  oa.z = za.z + (a.z - mean) * rs; oa.w = za.w + (a.w - mean) * rs;
  ob2.x = zb.x + (b.x - mean) * rs; ob2.y = zb.y + (b.y - mean) * rs;
  ob2.z = zb.z + (b.z - mean) * rs; ob2.w = zb.w + (b.w - mean) * rs;
  f[lane] = oa; f[lane + 64] = ob2;
  unsigned short* dbp = featb + (size_t)row * 512;
  *(ushort2*)&dbp[lane * 4] = pk2b(oa.x, oa.y);
  *(ushort2*)&dbp[lane * 4 + 2] = pk2b(oa.z, oa.w);
  *(ushort2*)&dbp[256 + lane * 4] = pk2b(ob2.x, ob2.y);
  *(ushort2*)&dbp[256 + lane * 4 + 2] = pk2b(ob2.z, ob2.w);
}

// dist with fused inorm128: one wave per row
__global__ __launch_bounds__(256) void dist2(const float* __restrict__ fq,
                                             const float* __restrict__ hi,
                                             const float* __restrict__ ne,
                                             float* __restrict__ out) {
  const int row = blockIdx.x * 4 + (threadIdx.x >> 6);
  const int lane = threadIdx.x & 63;
  float f0 = fq[(size_t)row * 128 + lane];
  float f1 = fq[(size_t)row * 128 + 64 + lane];
  float mean = wave_sum(f0 + f1) * (1.f / 128.f);
  float vs = (f0 - mean) * (f0 - mean) + (f1 - mean) * (f1 - mean);
  float rs = rsqrtf(wave_sum(vs) * (1.f / 128.f) + EPS);
  f0 = (f0 - mean) * rs;
  f1 = (f1 - mean) * rs;
  float mp = 1e30f, mn = 1e30f;
  for (int p = 0; p < 40; ++p) {
    float h0 = hi[p * 128 + lane], h1 = hi[p * 128 + 64 + lane];
    float d0 = f0 - h0, d1 = f1 - h1;
    float d2 = wave_sum(d0 * d0 + d1 * d1);
    mp = fminf(mp, d2);
    float n0 = ne[p * 128 + lane], n1 = ne[p * 128 + 64 + lane];
    d0 = f0 - n0; d1 = f1 - n1;
    d2 = wave_sum(d0 * d0 + d1 * d1);
    mn = fminf(mn, d2);
  }
  if (lane == 0) {
    out[row * 2 + 0] = -sqrtf(mn);
    out[row * 2 + 1] = -sqrtf(mp);
  }
}

extern "C" void kernel_launch(void* const* d_in, const int* in_sizes, int n_in,
                              void* d_out, int out_size, void* d_ws, size_t ws_size,
                              hipStream_t stream) {
  const float* x        = (const float*)d_in[0];
  const float* reduce_w = (const float*)d_in[1];
  const float* reduce_b = (const float*)d_in[2];
  const float* in_w     = (const float*)d_in[3];
  const float* in_b     = (const float*)d_in[4];
  const float* out_w    = (const float*)d_in[5];
  const float* out_b    = (const float*)d_in[6];
  const float* ff1_w    = (const float*)d_in[7];
  const float* ff1_b    = (const float*)d_in[8];
  const float* ff2_w    = (const float*)d_in[9];
  const float* ff2_b    = (const float*)d_in[10];
  const float* ln1_w    = (const float*)d_in[11];
  const float* ln1_b    = (const float*)d_in[12];
  const float* ln2_w    = (const float*)d_in[13];
  const float* ln2_b    = (const float*)d_in[14];
  const float* mlp_w1   = (const float*)d_in[15];
  const float* mlp_b1   = (const float*)d_in[16];
  const float* mlp_w2   = (const float*)d_in[17];
  const float* mlp_b2   = (const float*)d_in[18];
  const float* mlp_w3   = (const float*)d_in[19];
  const float* mlp_b3   = (const float*)d_in[20];
  const float* hi       = (const float*)d_in[21];
  const float* ne       = (const float*)d_in[22];
  float* out = (float*)d_out;
  float* ws = (float*)d_ws;

  const size_t MD = (size_t)2048 * 512;  // 1M elems
  float* feat0_f = ws;                // MD
  float* feat_f  = ws + MD;           // MD
  float* tmp_f   = ws + 2 * MD;       // MD
  float* pm      = ws + 3 * MD;       // 4*8*2048 = 65536 f32
  unsigned short* u = (unsigned short*)(ws + 3 * MD + 65536);
  unsigned short* qkv_b   = u;            // 3*MD
  unsigned short* feat0_b = u + 3 * MD;   // MD
  unsigned short* feat_b  = u + 4 * MD;   // MD
  unsigned short* relu_b  = u + 5 * MD;   // MD
  unsigned short* po_b    = u + 6 * MD;   // 4*8*2048*64 = 4*MD
  unsigned short* relu2_b = qkv_b;        // alias: attention done by then
  float* featq_f = tmp_f;

  // bf16 weight region
  unsigned short* wb = u + 10 * MD;
  unsigned short* reduce_wb = wb;                   // 393216
  unsigned short* in_wb     = wb + 393216;          // 2359296
  unsigned short* out_wb    = in_wb + 2359296;      // 786432
  unsigned short* ff1_wb    = out_wb + 786432;      // 786432
  unsigned short* ff2_wb    = ff1_wb + 786432;      // 786432
  unsigned short* mlp_w1b   = ff2_wb + 786432;      // 262144
  unsigned short* mlp_w2b   = mlp_w1b + 262144;     // 262144
  unsigned short* mlp_w3b   = mlp_w2b + 262144;     // 65536

  dim3 blk(256);
  WConvArgs wa;
  wa.src[0] = reduce_w; wa.dst[0] = reduce_wb; wa.n[0] = 393216;
  wa.src[1] = in_w;     wa.dst[1] = in_wb;     wa.n[1] = 2359296;
  wa.src[2] = out_w;    wa.dst[2] = out_wb;    wa.n[2] = 786432;
  wa.src[3] = ff1_w;    wa.dst[3] = ff1_wb;    wa.n[3] = 786432;
  wa.src[4] = ff2_w;    wa.dst[4] = ff2_wb;    wa.n[4] = 786432;
  wa.src[5] = mlp_w1;   wa.dst[5] = mlp_w1b;   wa.n[5] = 262144;
  wa.src[6] = mlp_w2;   wa.dst[6] = mlp_w2b;   wa.n[6] = 262144;
  wa.src[7] = mlp_w3;   wa.dst[7] = mlp_w3b;   wa.n[7] = 65536;
  conv_w<<<dim3(2304, 8), blk, 0, stream>>>(wa);

  gemm32<0, 1, 1, 0, 0, 0, 0><<<dim3(64, 8), blk, 0, stream>>>(
      x, nullptr, reduce_wb, reduce_b, nullptr, feat0_f, nullptr, 2048, 512, 768);
  inorm512<<<512, blk, 0, stream>>>(feat0_f, feat0_b, feat0_f);

  for (int i = 0; i < 3; ++i) {
    const float* fin_f = (i == 0) ? feat0_f : feat_f;
    const unsigned short* fin_b = (i == 0) ? feat0_b : feat_b;
    gemm32<0, 0, 0, 1, 0, 0, 1><<<dim3(64, 24), blk, 0, stream>>>(
        fin_b, nullptr, in_wb + (size_t)i * 1536 * 512, in_b + i * 1536,
        nullptr, nullptr, qkv_b, 2048, 1536, 512);
    flash_attn9<<<dim3(32, 8, 4), blk, 0, stream>>>(qkv_b, pm, po_b);
    gemm32<0, 0, 1, 0, 1, 1, 0><<<dim3(64, 8), blk, 0, stream>>>(
        po_b, pm, out_wb + (size_t)i * 512 * 512, out_b + i * 512,
        fin_f, tmp_f, nullptr, 2048, 512, 512);
    ln_res2<<<512, blk, 0, stream>>>(feat_f, feat_b, tmp_f,
                                     ln1_w + i * 512, ln1_b + i * 512);
    gemm32<1, 0, 0, 1, 0, 0, 0><<<dim3(64, 8), blk, 0, stream>>>(
        feat_b, nullptr, ff1_wb + (size_t)i * 512 * 512, ff1_b + i * 512,
        nullptr, nullptr, relu_b, 2048, 512, 512);
    gemm32<0, 0, 1, 0, 0, 1, 0><<<dim3(64, 8), blk, 0, stream>>>(
        relu_b, nullptr, ff2_wb + (size_t)i * 512 * 512, ff2_b + i * 512,
        feat_f, tmp_f, nullptr, 2048, 512, 512);
    ln_res2<<<512, blk, 0, stream>>>(feat_f, feat_b, tmp_f,
                                     ln2_w + i * 512, ln2_b + i * 512);
  }

  add_inorm<<<512, blk, 0, stream>>>(feat_f, feat_b, feat0_f);
  gemm32<1, 0, 0, 1, 0, 0, 0><<<dim3(64, 8), blk, 0, stream>>>(
      feat_b, nullptr, mlp_w1b, mlp_b1, nullptr, nullptr, relu_b, 2048, 512, 512);
  gemm32<1, 0, 0, 1, 0, 0, 0><<<dim3(64, 8), blk, 0, stream>>>(
      relu_b, nullptr, mlp_w2b, mlp_b2, nullptr, nullptr, relu2_b, 2048, 512, 512);
  gemm32<0, 0, 1, 0, 0, 0, 0><<<dim3(64, 2), blk, 0, stream>>>(
      relu2_b, nullptr, mlp_w3b, mlp_b3, nullptr, featq_f, nullptr, 2048, 128, 512);
  dist2<<<512, blk, 0, stream>>>(featq_f, hi, ne, out);
}